// Round 18
// baseline (366.821 us; speedup 1.0000x reference)
//
#include <hip/hip_runtime.h>
#include <hip/hip_bf16.h>

// ---------- helpers ----------

__device__ __forceinline__ unsigned short f2bf(float f) {
    unsigned u = __float_as_uint(f);
    unsigned r = u + 0x7fffu + ((u >> 16) & 1u);
    return (unsigned short)(r >> 16);
}

typedef __bf16 bf16_t;
typedef bf16_t bf16x8 __attribute__((ext_vector_type(8)));
typedef float f32x16 __attribute__((ext_vector_type(16)));

typedef const __attribute__((address_space(1))) unsigned int* gptr_t;
typedef __attribute__((address_space(3))) unsigned int* lptr_t;

__device__ __forceinline__ void gload_lds16(const void* g, void* l) {
    __builtin_amdgcn_global_load_lds((gptr_t)g, (lptr_t)l, 16, 0, 0);
}

// ---------- kernel 1: fused column-max of |x| AND column-max+convert of W ----------
__global__ void maxes_kernel(const float* __restrict__ x, int xrows,
                             const float* __restrict__ W, int wrows,
                             unsigned int* __restrict__ ma, unsigned int* __restrict__ mw,
                             unsigned short* __restrict__ Wb, int cols, int xBlocks) {
    int c = (blockIdx.x * blockDim.x + threadIdx.x) * 4;
    if (c >= cols) return;
    float m0 = 0.f, m1 = 0.f, m2 = 0.f, m3 = 0.f;
    if ((int)blockIdx.y < xBlocks) {
        int r0 = blockIdx.y * 64;
        int r1 = min(r0 + 64, xrows);
        const float* p = x + (size_t)r0 * cols + c;
        for (int r = r0; r < r1; ++r, p += cols) {
            float4 v = *(const float4*)p;
            m0 = fmaxf(m0, fabsf(v.x));
            m1 = fmaxf(m1, fabsf(v.y));
            m2 = fmaxf(m2, fabsf(v.z));
            m3 = fmaxf(m3, fabsf(v.w));
        }
        atomicMax(ma + c + 0, __float_as_uint(m0));
        atomicMax(ma + c + 1, __float_as_uint(m1));
        atomicMax(ma + c + 2, __float_as_uint(m2));
        atomicMax(ma + c + 3, __float_as_uint(m3));
    } else {
        int r0 = ((int)blockIdx.y - xBlocks) * 64;
        int r1 = min(r0 + 64, wrows);
        const float* p = W + (size_t)r0 * cols + c;
        unsigned short* q = Wb + (size_t)r0 * cols + c;
        for (int r = r0; r < r1; ++r, p += cols, q += cols) {
            float4 v = *(const float4*)p;
            ushort4 o;
            o.x = f2bf(v.x); o.y = f2bf(v.y); o.z = f2bf(v.z); o.w = f2bf(v.w);
            *(ushort4*)q = o;
            m0 = fmaxf(m0, fabsf(v.x));
            m1 = fmaxf(m1, fabsf(v.y));
            m2 = fmaxf(m2, fabsf(v.z));
            m3 = fmaxf(m3, fabsf(v.w));
        }
        atomicMax(mw + c + 0, __float_as_uint(m0));
        atomicMax(mw + c + 1, __float_as_uint(m1));
        atomicMax(mw + c + 2, __float_as_uint(m2));
        atomicMax(mw + c + 3, __float_as_uint(m3));
    }
}

// ---------- kernel 2: 2:4 prune of (x/s), s computed inline ----------
__global__ void prune_kernel(const float* __restrict__ x,
                             const unsigned int* __restrict__ ma,
                             const unsigned int* __restrict__ mw,
                             unsigned short* __restrict__ xsp, size_t ngroups, int cols) {
    size_t g = (size_t)blockIdx.x * blockDim.x + threadIdx.x;
    size_t stride = (size_t)gridDim.x * blockDim.x;
    for (; g < ngroups; g += stride) {
        size_t e = g * 4;
        int cb = (int)(e & (size_t)(cols - 1));
        float4 v = *(const float4*)(x + e);
        uint4 mav = *(const uint4*)(ma + cb);
        uint4 mwv = *(const uint4*)(mw + cb);
        float s0 = sqrtf(__uint_as_float(mav.x) / fmaxf(__uint_as_float(mwv.x), 1e-8f));
        float s1 = sqrtf(__uint_as_float(mav.y) / fmaxf(__uint_as_float(mwv.y), 1e-8f));
        float s2 = sqrtf(__uint_as_float(mav.z) / fmaxf(__uint_as_float(mwv.z), 1e-8f));
        float s3 = sqrtf(__uint_as_float(mav.w) / fmaxf(__uint_as_float(mwv.w), 1e-8f));
        float a0 = fabsf(v.x / s0);
        float a1 = fabsf(v.y / s1);
        float a2 = fabsf(v.z / s2);
        float a3 = fabsf(v.w / s3);
        int r0 = 0, r1 = 0, r2 = 0, r3 = 0;
        if (a1 > a0) r0++; else r1++;
        if (a2 > a0) r0++; else r2++;
        if (a3 > a0) r0++; else r3++;
        if (a2 > a1) r1++; else r2++;
        if (a3 > a1) r1++; else r3++;
        if (a3 > a2) r2++; else r3++;
        ushort4 o;
        o.x = (r0 < 2) ? f2bf(v.x) : (unsigned short)0;
        o.y = (r1 < 2) ? f2bf(v.y) : (unsigned short)0;
        o.z = (r2 < 2) ? f2bf(v.z) : (unsigned short)0;
        o.w = (r3 < 2) ? f2bf(v.w) : (unsigned short)0;
        *(ushort4*)(xsp + e) = o;
    }
}

// ---------- kernel 3: 256x256 bf16 B^T GEMM, 2 phases/K-tile, 32x32x16 MFMA ----------
// R17 structure byte-identical in staging/swizzle/sync/ledger; ONLY the MFMA
// shape changes 16x16x32 -> 32x32x16 (mubench 2382 vs 2075 TF: MFMA-pipe work
// per K-tile 2483 -> 2165 CU-cy). Same 24 ds_read_b128/wave/K-tile; chunk
// index c = kk*2 + (l>>5) (was kk*4 + (l>>4)); operand row = base + (l&31).
// Operand + C/D layouts validated end-to-end by R3's passing run.

template <int ISB, int H>
__device__ __forceinline__ void stage_half(const unsigned short* __restrict__ G, int ldk,
                                           long blockBase, int k0, unsigned short* sbuf,
                                           int wid, int l) {
#pragma unroll
    for (int j = 0; j < 2; ++j) {
        int rho0;
        if (ISB) rho0 = ((wid * 8) & 31) + (wid >> 2) * 64 + H * 32 + j * 128;
        else     rho0 = wid * 8 + H * 64 + j * 128;
        int rho = rho0 + (l >> 3);
        int c = l & 7;
        const unsigned short* src =
            G + (size_t)(blockBase + rho) * ldk + k0 + ((c ^ (rho & 7)) << 3);
        gload_lds16(src, (char*)sbuf + rho0 * 128);
    }
}

#define STAGE_A0(k, buf) stage_half<0, 0>(A, K, browBase, (k), (buf), wid, l)
#define STAGE_A1(k, buf) stage_half<0, 1>(A, K, browBase, (k), (buf), wid, l)
#define STAGE_B0(k, buf) stage_half<1, 0>(B, K, bcolBase, (k), (buf), wid, l)
#define STAGE_B1(k, buf) stage_half<1, 1>(B, K, bcolBase, (k), (buf), wid, l)

// A fragments for M-half MH: 2 M-frags of 32 rows x 4 k-slices of 16.
// row = wr*128 + MH*64 + mm*32 + (l&31); 16B chunk c = kk*2 + (l>>5).
#define LOAD_AF(dst, MH, srcbuf)                                                    \
    _Pragma("unroll") for (int mm = 0; mm < 2; ++mm)                                \
        _Pragma("unroll") for (int kk = 0; kk < 4; ++kk) {                          \
        int row = wr * 128 + (MH) * 64 + mm * 32 + (l & 31);                        \
        int cl = kk * 2 + (l >> 5);                                                 \
        dst[mm][kk] = *(const bf16x8*)((const char*)(srcbuf) + row * 128 +          \
                                       ((cl ^ (row & 7)) << 4));                    \
    }

// B fragment NH (32 cols): row = wc*64 + NH*32 + (l&31); 4 k-slices.
#define LOAD_BV(dst, NH, srcbuf)                                                    \
    _Pragma("unroll") for (int kk = 0; kk < 4; ++kk) {                              \
        int row = wc * 64 + (NH) * 32 + (l & 31);                                   \
        int cl = kk * 2 + (l >> 5);                                                 \
        dst[kk] = *(const bf16x8*)((const char*)(srcbuf) + row * 128 +              \
                                   ((cl ^ (row & 7)) << 4));                        \
    }

#define MFMA_NHALF(MH, AFS, BV0, BV1)                                               \
    _Pragma("unroll") for (int mm = 0; mm < 2; ++mm)                                \
        _Pragma("unroll") for (int kk = 0; kk < 4; ++kk) {                          \
        acc[(MH) * 2 + mm][0] = __builtin_amdgcn_mfma_f32_32x32x16_bf16(            \
            AFS[mm][kk], BV0[kk], acc[(MH) * 2 + mm][0], 0, 0, 0);                  \
        acc[(MH) * 2 + mm][1] = __builtin_amdgcn_mfma_f32_32x32x16_bf16(            \
            AFS[mm][kk], BV1[kk], acc[(MH) * 2 + mm][1], 0, 0, 0);                  \
    }

#define ITER(t, AF0, BV0, BV1, AF0N, BV0N, BV1N)                                    \
    {                                                                               \
        const int cur = (t) & 1;                                                    \
        const unsigned short* curA = sA[cur];                                       \
        const unsigned short* oAc = sA[cur ^ 1];                                    \
        const unsigned short* oBc = sB[cur ^ 1];                                    \
        unsigned short* oA = (unsigned short*)sA[cur ^ 1];                          \
        unsigned short* oB = (unsigned short*)sB[cur ^ 1];                          \
        unsigned short* cA = (unsigned short*)sA[cur];                              \
        unsigned short* cB = (unsigned short*)sB[cur];                              \
        const int k1 = ((t) + 1 < NT ? (t) + 1 : NT - 1) << 6;                      \
        const int k2 = ((t) + 2 < NT ? (t) + 2 : NT - 1) << 6;                      \
        /* ---- p1: M-half 0 ---- */                                                \
        STAGE_B0(k1, oB);                                                           \
        STAGE_A1(k1, oA);                                                           \
        __builtin_amdgcn_s_barrier();                                               \
        __builtin_amdgcn_s_setprio(1);                                              \
        LOAD_AF(af1, 1, curA);                                                      \
        MFMA_NHALF(0, AF0, BV0, BV1);                                               \
        __builtin_amdgcn_s_setprio(0);                                              \
        __builtin_amdgcn_sched_barrier(0);                                          \
        /* ---- p2: M-half 1, bv reused from registers ---- */                      \
        STAGE_A0(k2, cA);                                                           \
        STAGE_B1(k2, cB);                                                           \
        asm volatile("s_waitcnt vmcnt(4)");                                         \
        __builtin_amdgcn_s_barrier();                                               \
        __builtin_amdgcn_s_setprio(1);                                              \
        LOAD_AF(AF0N, 0, oAc);                                                      \
        MFMA_NHALF(1, af1, BV0, BV1);                                               \
        __builtin_amdgcn_s_setprio(0);                                              \
        __builtin_amdgcn_sched_barrier(0);                                          \
        /* ---- tail: bv prefetch for t+1 ---- */                                   \
        LOAD_BV(BV0N, 0, oBc);                                                      \
        LOAD_BV(BV1N, 1, oBc);                                                      \
        __builtin_amdgcn_sched_barrier(0);                                          \
    }

__global__ __launch_bounds__(512, 2) void gemm_bt256(
        const unsigned short* __restrict__ A,
        const unsigned short* __restrict__ B,
        float* __restrict__ C, int M, int N, int K) {
    __shared__ unsigned short sA[2][256 * 64];
    __shared__ unsigned short sB[2][256 * 64];
    const int tid = threadIdx.x;
    const int l = tid & 63;
    const int wid = tid >> 6;
    const int wr = wid >> 2;
    const int wc = wid & 3;

    // bijective XCD swizzle (nwg % 8 == 0); by-fastest for B-panel L2 locality
    const int nbx = N >> 8, nby = M >> 8;
    const int cpx = (nbx * nby) >> 3;
    const int swz = ((int)blockIdx.x & 7) * cpx + ((int)blockIdx.x >> 3);
    const int by = swz % nby;
    const int bx = swz / nby;
    const long browBase = (long)by << 8;
    const long bcolBase = (long)bx << 8;

    const int NT = K >> 6;

    f32x16 acc[4][2] = {};
    bf16x8 afA[2][4], bvA0[4], bvA1[4];
    bf16x8 afB[2][4], bvB0[4], bvB1[4];
    bf16x8 af1[2][4];

    // prologue: tile0 (8 loads) + A0(1),B1(1) (4 loads); vmcnt(4) drains tile0,
    // leaves A0,B1(1) in flight == steady-state p1-entry FIFO shape.
    STAGE_A0(0, sA[0]);
    STAGE_B0(0, sB[0]);
    STAGE_B1(0, sB[0]);
    STAGE_A1(0, sA[0]);
    STAGE_A0(64, sA[1]);
    STAGE_B1(64, sB[1]);
    asm volatile("s_waitcnt vmcnt(4)");
    __builtin_amdgcn_s_barrier();
    __builtin_amdgcn_sched_barrier(0);

    // preloop: tile0's p1 operand set
    LOAD_AF(afA, 0, sA[0]);
    LOAD_BV(bvA0, 0, sB[0]);
    LOAD_BV(bvA1, 1, sB[0]);
    __builtin_amdgcn_sched_barrier(0);

    for (int t = 0; t < NT; t += 2) {
        ITER(t, afA, bvA0, bvA1, afB, bvB0, bvB1);
        ITER(t + 1, afB, bvB0, bvB1, afA, bvA0, bvA1);
    }

    // drain in-flight dummy stages / dummy prefetch reads before epilogue
    asm volatile("s_waitcnt vmcnt(0) lgkmcnt(0)");

    // epilogue: 32x32 C/D layout: col = lane&31, row = (r&3) + 8*(r>>2) + 4*(lane>>5)
    const int ec = l & 31;
    const int erh = (l >> 5) * 4;
#pragma unroll
    for (int mi = 0; mi < 4; ++mi) {
#pragma unroll
        for (int n = 0; n < 2; ++n) {
            long row0 = browBase + wr * 128 + mi * 32;
            long col = bcolBase + wc * 64 + n * 32 + ec;
#pragma unroll
            for (int r = 0; r < 16; ++r) {
                long row = row0 + (r & 3) + 8 * (r >> 2) + erh;
                C[row * N + col] = acc[mi][n][r];
            }
        }
    }
}

// ---------- launch ----------
extern "C" void kernel_launch(void* const* d_in, const int* in_sizes, int n_in,
                              void* d_out, int out_size, void* d_ws, size_t ws_size,
                              hipStream_t stream) {
    const float* x = (const float*)d_in[0];
    const float* W = (const float*)d_in[1];
    float* out = (float*)d_out;

    const int K = 4096;
    const int Nout = in_sizes[1] / K;             // 4096
    const size_t Mrows = (size_t)in_sizes[0] / K; // 8192

    char* ws = (char*)d_ws;
    unsigned short* Xsp = (unsigned short*)ws;
    unsigned short* Wb = (unsigned short*)(ws + Mrows * K * 2);
    unsigned int* ma = (unsigned int*)(ws + Mrows * K * 2 + (size_t)Nout * K * 2);
    unsigned int* mw = ma + K;

    hipMemsetAsync(ma, 0, 2 * K * sizeof(unsigned int), stream);

    dim3 blk(256);
    {
        int xBlocks = (int)(Mrows / 64);              // 128
        int wBlocks = Nout / 64;                      // 64
        dim3 g(K / 1024, xBlocks + wBlocks);
        maxes_kernel<<<g, blk, 0, stream>>>(x, (int)Mrows, W, Nout, ma, mw, Wb, K, xBlocks);
    }
    {
        size_t ngroups = Mrows * K / 4;
        prune_kernel<<<dim3(2048), blk, 0, stream>>>(x, ma, mw, Xsp, ngroups, K);
    }
    {
        dim3 g((unsigned)((Mrows / 256) * (Nout / 256)));
        gemm_bt256<<<g, dim3(512), 0, stream>>>(Xsp, Wb, out, (int)Mrows, Nout, K);
    }
}